// Round 5
// baseline (1009.519 us; speedup 1.0000x reference)
//
#include <hip/hip_runtime.h>

#define NB    256
#define NIN   128
#define DD    256
#define NOUT  32
#define HDIM  64
#define EPS   1e-8f

typedef __attribute__((ext_vector_type(8))) short short8v;
typedef __attribute__((ext_vector_type(4))) float float4v;

__device__ __forceinline__ unsigned short f2bf(float f) {
    unsigned u = __float_as_uint(f);
    u += 0x7fffu + ((u >> 16) & 1u);
    return (unsigned short)(u >> 16);
}
__device__ __forceinline__ float bf2f(unsigned short h) {
    return __uint_as_float(((unsigned)h) << 16);
}

// ---------------------------------------------------------------------------
// K1: u = squash(x·Wcap + Bcap) -> u_hi/u_lo (bf16 split), ai = ||u||
// ---------------------------------------------------------------------------
__global__ __launch_bounds__(256, 2) void k_u_ai(
    const float* __restrict__ x, const float* __restrict__ Wcap,
    const float* __restrict__ Bcap, unsigned short* __restrict__ u_hi,
    unsigned short* __restrict__ u_lo, float* __restrict__ ai)
{
    const int i  = blockIdx.x;          // 0..127
    const int n0 = blockIdx.y * 64;     // 0,64,128,192
    const int t  = threadIdx.x;

    __shared__ float Wl[128][68];       // half of Wcap[i]: [128 d][64 h]
    __shared__ float xl[64][132];       // x tile: [64 n][128 d]

    const int tn = t >> 4, th = t & 15;
    const int hbase = th * 4;

    float acc[4][4];
    {
        const float4 b = *(const float4*)(Bcap + i * 64 + hbase);
        #pragma unroll
        for (int r = 0; r < 4; ++r) { acc[r][0]=b.x; acc[r][1]=b.y; acc[r][2]=b.z; acc[r][3]=b.w; }
    }

    for (int half = 0; half < 2; ++half) {
        const float4* wsrc = (const float4*)(Wcap + (size_t)i * DD * 64 + (size_t)half * 128 * 64);
        #pragma unroll
        for (int p = 0; p < 8; ++p) {
            int k = t + p * 256;
            float4 v = wsrc[k];
            int d = k >> 4, h4 = (k & 15) * 4;
            *(float4*)&Wl[d][h4] = v;
        }
        #pragma unroll
        for (int p = 0; p < 8; ++p) {
            int k = t + p * 256;
            int row = k >> 5, c4 = (k & 31) * 4;
            float4 v = *(const float4*)(x + ((size_t)(n0 + row) * NIN + i) * DD + half * 128 + c4);
            *(float4*)&xl[row][c4] = v;
        }
        __syncthreads();
        #pragma unroll 4
        for (int d = 0; d < 128; ++d) {
            float a0 = xl[tn*4+0][d], a1 = xl[tn*4+1][d], a2 = xl[tn*4+2][d], a3 = xl[tn*4+3][d];
            float w0 = Wl[d][hbase+0], w1 = Wl[d][hbase+1], w2 = Wl[d][hbase+2], w3 = Wl[d][hbase+3];
            acc[0][0]=fmaf(a0,w0,acc[0][0]); acc[0][1]=fmaf(a0,w1,acc[0][1]); acc[0][2]=fmaf(a0,w2,acc[0][2]); acc[0][3]=fmaf(a0,w3,acc[0][3]);
            acc[1][0]=fmaf(a1,w0,acc[1][0]); acc[1][1]=fmaf(a1,w1,acc[1][1]); acc[1][2]=fmaf(a1,w2,acc[1][2]); acc[1][3]=fmaf(a1,w3,acc[1][3]);
            acc[2][0]=fmaf(a2,w0,acc[2][0]); acc[2][1]=fmaf(a2,w1,acc[2][1]); acc[2][2]=fmaf(a2,w2,acc[2][2]); acc[2][3]=fmaf(a2,w3,acc[2][3]);
            acc[3][0]=fmaf(a3,w0,acc[3][0]); acc[3][1]=fmaf(a3,w1,acc[3][1]); acc[3][2]=fmaf(a3,w2,acc[3][2]); acc[3][3]=fmaf(a3,w3,acc[3][3]);
        }
        __syncthreads();
    }

    #pragma unroll
    for (int r = 0; r < 4; ++r) {
        float s = acc[r][0]*acc[r][0] + acc[r][1]*acc[r][1] + acc[r][2]*acc[r][2] + acc[r][3]*acc[r][3];
        s += __shfl_xor(s, 1); s += __shfl_xor(s, 2); s += __shfl_xor(s, 4); s += __shfl_xor(s, 8);
        float n2 = s, nrm = sqrtf(n2);
        float f = (n2 / (n2 + 1.0f)) / (nrm + EPS);
        int n = n0 + tn * 4 + r;
        float v0 = f*acc[r][0], v1 = f*acc[r][1], v2 = f*acc[r][2], v3 = f*acc[r][3];
        unsigned short ha = f2bf(v0), hb = f2bf(v1), hc = f2bf(v2), hd = f2bf(v3);
        unsigned short la = f2bf(v0 - bf2f(ha)), lb = f2bf(v1 - bf2f(hb));
        unsigned short lc = f2bf(v2 - bf2f(hc)), ld = f2bf(v3 - bf2f(hd));
        size_t eo = ((size_t)n * NIN + i) * HDIM + hbase;
        *(uint2*)(u_hi + eo) = make_uint2((unsigned)ha | ((unsigned)hb << 16), (unsigned)hc | ((unsigned)hd << 16));
        *(uint2*)(u_lo + eo) = make_uint2((unsigned)la | ((unsigned)lb << 16), (unsigned)lc | ((unsigned)ld << 16));
        if (th == 0) ai[(size_t)n * NIN + i] = f * nrm;
    }
}

// ---------------------------------------------------------------------------
// K1b: Wv [io][d][h] f32 -> Wt_hi/Wt_lo [io][h][d] bf16 (transpose + split)
// ---------------------------------------------------------------------------
__global__ __launch_bounds__(256, 4) void k_wconv(
    const float* __restrict__ Wv, unsigned short* __restrict__ Wth,
    unsigned short* __restrict__ Wtl)
{
    const int io = blockIdx.x;
    const int t  = threadIdx.x;
    __shared__ float tile[64][68];

    const float4* src = (const float4*)(Wv + (size_t)io * 4096);
    const int d = t >> 2, hb = (t & 3) * 16;
    #pragma unroll
    for (int q = 0; q < 4; ++q) {
        float4 v = src[t * 4 + q];
        *(float4*)&tile[d][hb + q * 4] = v;
    }
    __syncthreads();
    const int h = t >> 2, d0 = (t & 3) * 16;
    unsigned hp[8], lp[8];
    #pragma unroll
    for (int j = 0; j < 8; ++j) {
        float fa = tile[d0 + 2*j][h], fb = tile[d0 + 2*j + 1][h];
        unsigned short ha = f2bf(fa), hbb = f2bf(fb);
        unsigned short la = f2bf(fa - bf2f(ha)), lb = f2bf(fb - bf2f(hbb));
        hp[j] = (unsigned)ha | ((unsigned)hbb << 16);
        lp[j] = (unsigned)la | ((unsigned)lb << 16);
    }
    size_t eo = (size_t)io * 4096 + (size_t)h * 64 + d0;
    *(uint4*)(Wth + eo)     = make_uint4(hp[0], hp[1], hp[2], hp[3]);
    *(uint4*)(Wth + eo + 8) = make_uint4(hp[4], hp[5], hp[6], hp[7]);
    *(uint4*)(Wtl + eo)     = make_uint4(lp[0], lp[1], lp[2], lp[3]);
    *(uint4*)(Wtl + eo + 8) = make_uint4(lp[4], lp[5], lp[6], lp[7]);
}

// ---------------------------------------------------------------------------
// K2: votes via split-bf16 MFMA. Block = (i, o-pair); loops n-chunks of 64.
// ---------------------------------------------------------------------------
__global__ __launch_bounds__(256, 3) void k_votes(
    const unsigned short* __restrict__ u_hi, const unsigned short* __restrict__ u_lo,
    const unsigned short* __restrict__ Wth, const unsigned short* __restrict__ Wtl,
    const float* __restrict__ Bv, const float* __restrict__ mask,
    float* __restrict__ votes, int c0, int cnt)
{
    const int i   = blockIdx.x;
    const int op  = blockIdx.y;
    const int t   = threadIdx.x;
    const int iob = i * 32 + op * 2;

    __shared__ __align__(16) char lds[49920];
    float* biasl = (float*)(lds + 49152);
    float* msk   = (float*)(lds + 49664);

    {   // stage B once
        const int o = t >> 7, cc = t & 127;
        #pragma unroll
        for (int q = 0; q < 4; ++q) {
            int c = cc + q * 128;
            int h = c >> 3, dby = (c & 7) * 16;
            size_t gb = (size_t)(iob + o) * 8192 + (size_t)c * 16;
            uint4 vh = *(const uint4*)((const char*)Wth + gb);
            uint4 vl = *(const uint4*)((const char*)Wtl + gb);
            int lb = o * 16384 + h * 128 + (dby ^ ((h & 7) << 4));
            *(uint4*)(lds + lb)        = vh;
            *(uint4*)(lds + lb + 8192) = vl;
        }
    }
    if (t < 128) biasl[t] = Bv[(size_t)(iob + (t >> 6)) * 64 + (t & 63)];

    const int w = t >> 6, lane = t & 63;
    const int o_l = w & 1, mi0 = (w >> 1) * 2;
    const int lr = lane & 15, lg = lane >> 4;

    const int nzn = (cnt + 63) >> 6;
    for (int nz = 0; nz < nzn; ++nz) {
        const int nbase = nz * 64;
        __syncthreads();
        {   // stage A
            const int n = t >> 2, s = t & 3;
            bool ok = (nbase + n) < cnt;
            size_t gb = ((size_t)(c0 + nbase + n) * NIN + i) * HDIM * 2;
            #pragma unroll
            for (int p = 0; p < 2; ++p) {
                int dby = s * 32 + p * 16;
                int lb = 32768 + n * 128 + (dby ^ ((n & 7) << 4));
                uint4 vh = ok ? *(const uint4*)((const char*)u_hi + gb + dby) : make_uint4(0,0,0,0);
                uint4 vl = ok ? *(const uint4*)((const char*)u_lo + gb + dby) : make_uint4(0,0,0,0);
                *(uint4*)(lds + lb)        = vh;
                *(uint4*)(lds + lb + 8192) = vl;
            }
        }
        if (t < 64) msk[t] = ((nbase + t) < cnt) ? mask[(size_t)(c0 + nbase + t) * NIN + i] : 0.f;
        __syncthreads();

        float4v acc[2][4];
        #pragma unroll
        for (int a = 0; a < 2; ++a)
            #pragma unroll
            for (int b = 0; b < 4; ++b)
                acc[a][b] = (float4v){0.f, 0.f, 0.f, 0.f};

        #pragma unroll
        for (int ks = 0; ks < 2; ++ks) {
            const int colby = ks * 64 + lg * 16;
            short8v ah[2], al[2], bh[4], bl[4];
            #pragma unroll
            for (int mi = 0; mi < 2; ++mi) {
                int row = (mi0 + mi) * 16 + lr;
                int ob = 32768 + row * 128 + (colby ^ ((row & 7) << 4));
                ah[mi] = *(const short8v*)(lds + ob);
                al[mi] = *(const short8v*)(lds + ob + 8192);
            }
            #pragma unroll
            for (int ni = 0; ni < 4; ++ni) {
                int hrow = ni * 16 + lr;
                int ob = o_l * 16384 + hrow * 128 + (colby ^ ((hrow & 7) << 4));
                bh[ni] = *(const short8v*)(lds + ob);
                bl[ni] = *(const short8v*)(lds + ob + 8192);
            }
            #pragma unroll
            for (int mi = 0; mi < 2; ++mi)
                #pragma unroll
                for (int ni = 0; ni < 4; ++ni) {
                    acc[mi][ni] = __builtin_amdgcn_mfma_f32_16x16x32_bf16(ah[mi], bh[ni], acc[mi][ni], 0, 0, 0);
                    acc[mi][ni] = __builtin_amdgcn_mfma_f32_16x16x32_bf16(al[mi], bh[ni], acc[mi][ni], 0, 0, 0);
                    acc[mi][ni] = __builtin_amdgcn_mfma_f32_16x16x32_bf16(ah[mi], bl[ni], acc[mi][ni], 0, 0, 0);
                }
        }

        #pragma unroll
        for (int mi = 0; mi < 2; ++mi) {
            #pragma unroll
            for (int r = 0; r < 4; ++r) {
                int n_loc = (mi0 + mi) * 16 + lg * 4 + r;
                if (nbase + n_loc < cnt) {
                    float mv = msk[n_loc];
                    size_t ob = ((size_t)(nbase + n_loc) * NIN + i) * 2048 + (size_t)(op * 2 + o_l) * 64;
                    #pragma unroll
                    for (int ni = 0; ni < 4; ++ni) {
                        int h = ni * 16 + lr;
                        votes[ob + h] = (acc[mi][ni][r] + biasl[o_l * 64 + h]) * mv;
                    }
                }
            }
        }
    }
}

// ---------------------------------------------------------------------------
// K3 v4: 3-pass routing. 1024 threads = 16 waves, 8 i per wave (4 waves/SIMD).
// Per-thread live state ~115 floats (s[32]+vj[32]+vjp[32]+temps) < 128 VGPR.
// LDS = 148 KB forces 1 block/CU, so the compiler has NO occupancy incentive
// to allocate below 128 VGPR (R4 pathology: 34 KB LDS -> compiler picked 64
// VGPR to chase 2 blocks/CU and spilled 283 MB to scratch).
// Deterministic tree-merge via rotated BSLOT (2-way bank aliasing = free).
// ---------------------------------------------------------------------------
#define BSLOT(W, LN, J) buf[(W)][((LN) << 5) + (((J) + (LN)) & 31)]

#define LOADSLAB(DST, IDX) do {                                              \
    const float4* _p = (const float4*)(vb + (size_t)(IDX) * 2048 + base);    \
    _Pragma("unroll")                                                        \
    for (int _q = 0; _q < 8; ++_q) {                                         \
        float4 _v = _p[_q];                                                  \
        (DST)[_q*4+0]=_v.x; (DST)[_q*4+1]=_v.y;                              \
        (DST)[_q*4+2]=_v.z; (DST)[_q*4+3]=_v.w; }                            \
} while (0)

#define RBODY(V, I) do {                                                     \
    const int _i = (I);                                                      \
    float _ag = 0.f;                                                         \
    _Pragma("unroll")                                                        \
    for (int _j = 0; _j < 32; ++_j) _ag = fmaf((V)[_j], vj[_j], _ag);        \
    _ag += __shfl_xor(_ag, 1);                                               \
    float _b = bijl[_i][o] + _ag;                                            \
    if (g == 0) bijl[_i][o] = _b;                                            \
    float _m = _b;                                                           \
    _m = fmaxf(_m, __shfl_xor(_m, 2));  _m = fmaxf(_m, __shfl_xor(_m, 4));   \
    _m = fmaxf(_m, __shfl_xor(_m, 8));  _m = fmaxf(_m, __shfl_xor(_m, 16));  \
    _m = fmaxf(_m, __shfl_xor(_m, 32));                                      \
    _m = fmaxf(_m, 0.f);                                                     \
    float _e = __expf(_b - _m);                                              \
    float _es = _e;                                                          \
    _es += __shfl_xor(_es, 2);  _es += __shfl_xor(_es, 4);                   \
    _es += __shfl_xor(_es, 8);  _es += __shfl_xor(_es, 16);                  \
    _es += __shfl_xor(_es, 32);                                              \
    float _den = _es + __expf(-_m);                                          \
    float _c = ai_s[_i] * _e / _den;                                         \
    _Pragma("unroll")                                                        \
    for (int _j = 0; _j < 32; ++_j) vjp[_j] = fmaf(_c, (V)[_j], vjp[_j]);    \
} while (0)

#define RMERGE(WRITEOUT) do {                                                \
    __syncthreads();                                                         \
    _Pragma("unroll")                                                        \
    for (int _j = 0; _j < 32; ++_j) BSLOT(wv, lane, _j) = vjp[_j];           \
    __syncthreads();                                                         \
    if (wv == 0) {                                                           \
        float _tot[32];                                                      \
        _Pragma("unroll")                                                    \
        for (int _j = 0; _j < 32; ++_j) {                                    \
            float _s = 0.f;                                                  \
            _Pragma("unroll")                                                \
            for (int _w = 0; _w < 16; ++_w) _s += BSLOT(_w, lane, _j);       \
            _tot[_j] = _s; }                                                 \
        float _ss = 0.f;                                                     \
        _Pragma("unroll")                                                    \
        for (int _j = 0; _j < 32; ++_j) _ss = fmaf(_tot[_j], _tot[_j], _ss); \
        _ss += __shfl_xor(_ss, 1);                                           \
        float _nr = sqrtf(_ss);                                              \
        float _f = (_ss / (_ss + 1.0f)) / (_nr + EPS);                       \
        _Pragma("unroll")                                                    \
        for (int _j = 0; _j < 32; ++_j) {                                    \
            float _v = _f * _tot[_j];                                        \
            BSLOT(0, lane, _j) = _v;                                         \
            if (WRITEOUT) out[(size_t)n * 2048 + base + _j] = _v;            \
        }                                                                    \
    }                                                                        \
    __syncthreads();                                                         \
    _Pragma("unroll")                                                        \
    for (int _j = 0; _j < 32; ++_j) vj[_j] = BSLOT(0, lane, _j);             \
} while (0)

__global__ __launch_bounds__(1024, 4) void k_route(
    const float* __restrict__ votes, const float* __restrict__ ai,
    float* __restrict__ out, int n0, int cnt)
{
    const int nl = blockIdx.x;
    const int n  = n0 + nl;
    const int t  = threadIdx.x;
    const int wv = t >> 6;          // 0..15
    const int lane = t & 63;
    const int o = lane >> 1;
    const int g = lane & 1;
    const int base = o * HDIM + g * 32;
    const int ib = wv * 8;

    __shared__ float buf[16][2048];     // 128 KB merge buffer (forces 1 blk/CU)
    __shared__ float bijl[NIN][NOUT + 1];
    __shared__ float ai_s[NIN];

    if (t < NIN) ai_s[t] = ai[(size_t)n * NIN + t];
    for (int idx = t; idx < NIN * (NOUT + 1); idx += 1024) ((float*)bijl)[idx] = 0.f;
    __syncthreads();

    const float* vb = votes + (size_t)nl * (NIN * NOUT * HDIM);

    float s[32], vj[32], vjp[32];

    // ---- pass 1: uniform coupling c = ai/33 ----
    #pragma unroll
    for (int j = 0; j < 32; ++j) vjp[j] = 0.f;
    #pragma unroll
    for (int k = 0; k < 8; ++k) {
        LOADSLAB(s, ib + k);
        float c = ai_s[ib + k] * (1.0f / 33.0f);
        #pragma unroll
        for (int j = 0; j < 32; ++j) vjp[j] = fmaf(c, s[j], vjp[j]);
    }
    RMERGE(false);

    // ---- pass 2 ----
    #pragma unroll
    for (int j = 0; j < 32; ++j) vjp[j] = 0.f;
    #pragma unroll
    for (int k = 0; k < 8; ++k) {
        LOADSLAB(s, ib + k);
        RBODY(s, ib + k);
    }
    RMERGE(false);

    // ---- pass 3 ----
    #pragma unroll
    for (int j = 0; j < 32; ++j) vjp[j] = 0.f;
    #pragma unroll
    for (int k = 0; k < 8; ++k) {
        LOADSLAB(s, ib + k);
        RBODY(s, ib + k);
    }
    RMERGE(true);
}

// ---------------------------------------------------------------------------
extern "C" void kernel_launch(void* const* d_in, const int* in_sizes, int n_in,
                              void* d_out, int out_size, void* d_ws, size_t ws_size,
                              hipStream_t stream)
{
    const float* x    = (const float*)d_in[0];
    const float* mask = (const float*)d_in[1];
    const float* Wcap = (const float*)d_in[2];
    const float* Bcap = (const float*)d_in[3];
    const float* Wv   = (const float*)d_in[4];
    const float* Bv   = (const float*)d_in[5];
    float* out = (float*)d_out;

    char* ws = (char*)d_ws;
    unsigned short* u_hi = (unsigned short*)ws;              //  4,194,304
    unsigned short* u_lo = (unsigned short*)(ws + 4194304);  //  4,194,304
    float*          ai   = (float*)(ws + 8388608);           //    131,072
    unsigned short* Wth  = (unsigned short*)(ws + 8519680);  // 33,554,432
    unsigned short* Wtl  = (unsigned short*)(ws + 42074112); // 33,554,432
    float*          votes= (float*)(ws + 75628544);          // chunk * 1 MB

    size_t avail = ws_size > 75628544ull ? ws_size - 75628544ull : 0;
    int chunk = 256;
    while (chunk > 4 && (size_t)chunk * 1048576ull > avail) chunk >>= 1;

    k_u_ai<<<dim3(NIN, 4), 256, 0, stream>>>(x, Wcap, Bcap, u_hi, u_lo, ai);
    k_wconv<<<NIN * NOUT, 256, 0, stream>>>(Wv, Wth, Wtl);

    for (int cc0 = 0; cc0 < NB; cc0 += chunk) {
        int cnt = (NB - cc0) < chunk ? (NB - cc0) : chunk;
        k_votes<<<dim3(NIN, 16), 256, 0, stream>>>(u_hi, u_lo, Wth, Wtl, Bv, mask, votes, cc0, cnt);
        k_route<<<cnt, 1024, 0, stream>>>(votes, ai, out, cc0, cnt);
    }
}

// Round 6
// 996.657 us; speedup vs baseline: 1.0129x; 1.0129x over previous
//
#include <hip/hip_runtime.h>

#define NB    256
#define NIN   128
#define DD    256
#define NOUT  32
#define HDIM  64
#define EPS   1e-8f

typedef __attribute__((ext_vector_type(8))) short short8v;
typedef __attribute__((ext_vector_type(4))) float float4v;

__device__ __forceinline__ unsigned short f2bf(float f) {
    unsigned u = __float_as_uint(f);
    u += 0x7fffu + ((u >> 16) & 1u);
    return (unsigned short)(u >> 16);
}
__device__ __forceinline__ float bf2f(unsigned short h) {
    return __uint_as_float(((unsigned)h) << 16);
}

// ---------------------------------------------------------------------------
// K1: u = squash(x·Wcap + Bcap) -> u_hi/u_lo (bf16 split), ai = ||u||
// ---------------------------------------------------------------------------
__global__ __launch_bounds__(256, 2) void k_u_ai(
    const float* __restrict__ x, const float* __restrict__ Wcap,
    const float* __restrict__ Bcap, unsigned short* __restrict__ u_hi,
    unsigned short* __restrict__ u_lo, float* __restrict__ ai)
{
    const int i  = blockIdx.x;          // 0..127
    const int n0 = blockIdx.y * 64;     // 0,64,128,192
    const int t  = threadIdx.x;

    __shared__ float Wl[128][68];       // half of Wcap[i]: [128 d][64 h]
    __shared__ float xl[64][132];       // x tile: [64 n][128 d]

    const int tn = t >> 4, th = t & 15;
    const int hbase = th * 4;

    float acc[4][4];
    {
        const float4 b = *(const float4*)(Bcap + i * 64 + hbase);
        #pragma unroll
        for (int r = 0; r < 4; ++r) { acc[r][0]=b.x; acc[r][1]=b.y; acc[r][2]=b.z; acc[r][3]=b.w; }
    }

    for (int half = 0; half < 2; ++half) {
        const float4* wsrc = (const float4*)(Wcap + (size_t)i * DD * 64 + (size_t)half * 128 * 64);
        #pragma unroll
        for (int p = 0; p < 8; ++p) {
            int k = t + p * 256;
            float4 v = wsrc[k];
            int d = k >> 4, h4 = (k & 15) * 4;
            *(float4*)&Wl[d][h4] = v;
        }
        #pragma unroll
        for (int p = 0; p < 8; ++p) {
            int k = t + p * 256;
            int row = k >> 5, c4 = (k & 31) * 4;
            float4 v = *(const float4*)(x + ((size_t)(n0 + row) * NIN + i) * DD + half * 128 + c4);
            *(float4*)&xl[row][c4] = v;
        }
        __syncthreads();
        #pragma unroll 4
        for (int d = 0; d < 128; ++d) {
            float a0 = xl[tn*4+0][d], a1 = xl[tn*4+1][d], a2 = xl[tn*4+2][d], a3 = xl[tn*4+3][d];
            float w0 = Wl[d][hbase+0], w1 = Wl[d][hbase+1], w2 = Wl[d][hbase+2], w3 = Wl[d][hbase+3];
            acc[0][0]=fmaf(a0,w0,acc[0][0]); acc[0][1]=fmaf(a0,w1,acc[0][1]); acc[0][2]=fmaf(a0,w2,acc[0][2]); acc[0][3]=fmaf(a0,w3,acc[0][3]);
            acc[1][0]=fmaf(a1,w0,acc[1][0]); acc[1][1]=fmaf(a1,w1,acc[1][1]); acc[1][2]=fmaf(a1,w2,acc[1][2]); acc[1][3]=fmaf(a1,w3,acc[1][3]);
            acc[2][0]=fmaf(a2,w0,acc[2][0]); acc[2][1]=fmaf(a2,w1,acc[2][1]); acc[2][2]=fmaf(a2,w2,acc[2][2]); acc[2][3]=fmaf(a2,w3,acc[2][3]);
            acc[3][0]=fmaf(a3,w0,acc[3][0]); acc[3][1]=fmaf(a3,w1,acc[3][1]); acc[3][2]=fmaf(a3,w2,acc[3][2]); acc[3][3]=fmaf(a3,w3,acc[3][3]);
        }
        __syncthreads();
    }

    #pragma unroll
    for (int r = 0; r < 4; ++r) {
        float s = acc[r][0]*acc[r][0] + acc[r][1]*acc[r][1] + acc[r][2]*acc[r][2] + acc[r][3]*acc[r][3];
        s += __shfl_xor(s, 1); s += __shfl_xor(s, 2); s += __shfl_xor(s, 4); s += __shfl_xor(s, 8);
        float n2 = s, nrm = sqrtf(n2);
        float f = (n2 / (n2 + 1.0f)) / (nrm + EPS);
        int n = n0 + tn * 4 + r;
        float v0 = f*acc[r][0], v1 = f*acc[r][1], v2 = f*acc[r][2], v3 = f*acc[r][3];
        unsigned short ha = f2bf(v0), hb = f2bf(v1), hc = f2bf(v2), hd = f2bf(v3);
        unsigned short la = f2bf(v0 - bf2f(ha)), lb = f2bf(v1 - bf2f(hb));
        unsigned short lc = f2bf(v2 - bf2f(hc)), ld = f2bf(v3 - bf2f(hd));
        size_t eo = ((size_t)n * NIN + i) * HDIM + hbase;
        *(uint2*)(u_hi + eo) = make_uint2((unsigned)ha | ((unsigned)hb << 16), (unsigned)hc | ((unsigned)hd << 16));
        *(uint2*)(u_lo + eo) = make_uint2((unsigned)la | ((unsigned)lb << 16), (unsigned)lc | ((unsigned)ld << 16));
        if (th == 0) ai[(size_t)n * NIN + i] = f * nrm;
    }
}

// ---------------------------------------------------------------------------
// K1b: Wv [io][d][h] f32 -> Wt_hi/Wt_lo [io][h][d] bf16 (transpose + split)
// ---------------------------------------------------------------------------
__global__ __launch_bounds__(256, 4) void k_wconv(
    const float* __restrict__ Wv, unsigned short* __restrict__ Wth,
    unsigned short* __restrict__ Wtl)
{
    const int io = blockIdx.x;
    const int t  = threadIdx.x;
    __shared__ float tile[64][68];

    const float4* src = (const float4*)(Wv + (size_t)io * 4096);
    const int d = t >> 2, hb = (t & 3) * 16;
    #pragma unroll
    for (int q = 0; q < 4; ++q) {
        float4 v = src[t * 4 + q];
        *(float4*)&tile[d][hb + q * 4] = v;
    }
    __syncthreads();
    const int h = t >> 2, d0 = (t & 3) * 16;
    unsigned hp[8], lp[8];
    #pragma unroll
    for (int j = 0; j < 8; ++j) {
        float fa = tile[d0 + 2*j][h], fb = tile[d0 + 2*j + 1][h];
        unsigned short ha = f2bf(fa), hbb = f2bf(fb);
        unsigned short la = f2bf(fa - bf2f(ha)), lb = f2bf(fb - bf2f(hbb));
        hp[j] = (unsigned)ha | ((unsigned)hbb << 16);
        lp[j] = (unsigned)la | ((unsigned)lb << 16);
    }
    size_t eo = (size_t)io * 4096 + (size_t)h * 64 + d0;
    *(uint4*)(Wth + eo)     = make_uint4(hp[0], hp[1], hp[2], hp[3]);
    *(uint4*)(Wth + eo + 8) = make_uint4(hp[4], hp[5], hp[6], hp[7]);
    *(uint4*)(Wtl + eo)     = make_uint4(lp[0], lp[1], lp[2], lp[3]);
    *(uint4*)(Wtl + eo + 8) = make_uint4(lp[4], lp[5], lp[6], lp[7]);
}

// ---------------------------------------------------------------------------
// K2: votes via split-bf16 MFMA. Block = (i, o-pair); loops n-chunks of 64.
// ---------------------------------------------------------------------------
__global__ __launch_bounds__(256, 3) void k_votes(
    const unsigned short* __restrict__ u_hi, const unsigned short* __restrict__ u_lo,
    const unsigned short* __restrict__ Wth, const unsigned short* __restrict__ Wtl,
    const float* __restrict__ Bv, const float* __restrict__ mask,
    float* __restrict__ votes, int c0, int cnt)
{
    const int i   = blockIdx.x;
    const int op  = blockIdx.y;
    const int t   = threadIdx.x;
    const int iob = i * 32 + op * 2;

    __shared__ __align__(16) char lds[49920];
    float* biasl = (float*)(lds + 49152);
    float* msk   = (float*)(lds + 49664);

    {   // stage B once
        const int o = t >> 7, cc = t & 127;
        #pragma unroll
        for (int q = 0; q < 4; ++q) {
            int c = cc + q * 128;
            int h = c >> 3, dby = (c & 7) * 16;
            size_t gb = (size_t)(iob + o) * 8192 + (size_t)c * 16;
            uint4 vh = *(const uint4*)((const char*)Wth + gb);
            uint4 vl = *(const uint4*)((const char*)Wtl + gb);
            int lb = o * 16384 + h * 128 + (dby ^ ((h & 7) << 4));
            *(uint4*)(lds + lb)        = vh;
            *(uint4*)(lds + lb + 8192) = vl;
        }
    }
    if (t < 128) biasl[t] = Bv[(size_t)(iob + (t >> 6)) * 64 + (t & 63)];

    const int w = t >> 6, lane = t & 63;
    const int o_l = w & 1, mi0 = (w >> 1) * 2;
    const int lr = lane & 15, lg = lane >> 4;

    const int nzn = (cnt + 63) >> 6;
    for (int nz = 0; nz < nzn; ++nz) {
        const int nbase = nz * 64;
        __syncthreads();
        {   // stage A
            const int n = t >> 2, s = t & 3;
            bool ok = (nbase + n) < cnt;
            size_t gb = ((size_t)(c0 + nbase + n) * NIN + i) * HDIM * 2;
            #pragma unroll
            for (int p = 0; p < 2; ++p) {
                int dby = s * 32 + p * 16;
                int lb = 32768 + n * 128 + (dby ^ ((n & 7) << 4));
                uint4 vh = ok ? *(const uint4*)((const char*)u_hi + gb + dby) : make_uint4(0,0,0,0);
                uint4 vl = ok ? *(const uint4*)((const char*)u_lo + gb + dby) : make_uint4(0,0,0,0);
                *(uint4*)(lds + lb)        = vh;
                *(uint4*)(lds + lb + 8192) = vl;
            }
        }
        if (t < 64) msk[t] = ((nbase + t) < cnt) ? mask[(size_t)(c0 + nbase + t) * NIN + i] : 0.f;
        __syncthreads();

        float4v acc[2][4];
        #pragma unroll
        for (int a = 0; a < 2; ++a)
            #pragma unroll
            for (int b = 0; b < 4; ++b)
                acc[a][b] = (float4v){0.f, 0.f, 0.f, 0.f};

        #pragma unroll
        for (int ks = 0; ks < 2; ++ks) {
            const int colby = ks * 64 + lg * 16;
            short8v ah[2], al[2], bh[4], bl[4];
            #pragma unroll
            for (int mi = 0; mi < 2; ++mi) {
                int row = (mi0 + mi) * 16 + lr;
                int ob = 32768 + row * 128 + (colby ^ ((row & 7) << 4));
                ah[mi] = *(const short8v*)(lds + ob);
                al[mi] = *(const short8v*)(lds + ob + 8192);
            }
            #pragma unroll
            for (int ni = 0; ni < 4; ++ni) {
                int hrow = ni * 16 + lr;
                int ob = o_l * 16384 + hrow * 128 + (colby ^ ((hrow & 7) << 4));
                bh[ni] = *(const short8v*)(lds + ob);
                bl[ni] = *(const short8v*)(lds + ob + 8192);
            }
            #pragma unroll
            for (int mi = 0; mi < 2; ++mi)
                #pragma unroll
                for (int ni = 0; ni < 4; ++ni) {
                    acc[mi][ni] = __builtin_amdgcn_mfma_f32_16x16x32_bf16(ah[mi], bh[ni], acc[mi][ni], 0, 0, 0);
                    acc[mi][ni] = __builtin_amdgcn_mfma_f32_16x16x32_bf16(al[mi], bh[ni], acc[mi][ni], 0, 0, 0);
                    acc[mi][ni] = __builtin_amdgcn_mfma_f32_16x16x32_bf16(ah[mi], bl[ni], acc[mi][ni], 0, 0, 0);
                }
        }

        #pragma unroll
        for (int mi = 0; mi < 2; ++mi) {
            #pragma unroll
            for (int r = 0; r < 4; ++r) {
                int n_loc = (mi0 + mi) * 16 + lg * 4 + r;
                if (nbase + n_loc < cnt) {
                    float mv = msk[n_loc];
                    size_t ob = ((size_t)(nbase + n_loc) * NIN + i) * 2048 + (size_t)(op * 2 + o_l) * 64;
                    #pragma unroll
                    for (int ni = 0; ni < 4; ++ni) {
                        int h = ni * 16 + lr;
                        votes[ob + h] = (acc[mi][ni][r] + biasl[o_l * 64 + h]) * mv;
                    }
                }
            }
        }
    }
}

// ---------------------------------------------------------------------------
// K3 v5: identical structure to v4 (R5), ONE change: pin the register
// allocator with amdgpu_waves_per_eu(4,4). R3/R4/R5 showed the allocator
// targets a fixed high occupancy (512thr->128 VGPR, 1024thr->64 VGPR) and
// spills the 96-float per-thread state regardless of launch_bounds min or
// LDS-forced 1 block/CU. Budget for exactly 4 waves/EU = 128 VGPR; demand
// (s[32]+vj[32]+vjp[32]+temps ~ 110) fits -> no scratch round-trip on s[].
// ---------------------------------------------------------------------------
#define BSLOT(W, LN, J) buf[(W)][((LN) << 5) + (((J) + (LN)) & 31)]

#define LOADSLAB(DST, IDX) do {                                              \
    const float4* _p = (const float4*)(vb + (size_t)(IDX) * 2048 + base);    \
    _Pragma("unroll")                                                        \
    for (int _q = 0; _q < 8; ++_q) {                                         \
        float4 _v = _p[_q];                                                  \
        (DST)[_q*4+0]=_v.x; (DST)[_q*4+1]=_v.y;                              \
        (DST)[_q*4+2]=_v.z; (DST)[_q*4+3]=_v.w; }                            \
} while (0)

#define RBODY(V, I) do {                                                     \
    const int _i = (I);                                                      \
    float _ag = 0.f;                                                         \
    _Pragma("unroll")                                                        \
    for (int _j = 0; _j < 32; ++_j) _ag = fmaf((V)[_j], vj[_j], _ag);        \
    _ag += __shfl_xor(_ag, 1);                                               \
    float _b = bijl[_i][o] + _ag;                                            \
    if (g == 0) bijl[_i][o] = _b;                                            \
    float _m = _b;                                                           \
    _m = fmaxf(_m, __shfl_xor(_m, 2));  _m = fmaxf(_m, __shfl_xor(_m, 4));   \
    _m = fmaxf(_m, __shfl_xor(_m, 8));  _m = fmaxf(_m, __shfl_xor(_m, 16));  \
    _m = fmaxf(_m, __shfl_xor(_m, 32));                                      \
    _m = fmaxf(_m, 0.f);                                                     \
    float _e = __expf(_b - _m);                                              \
    float _es = _e;                                                          \
    _es += __shfl_xor(_es, 2);  _es += __shfl_xor(_es, 4);                   \
    _es += __shfl_xor(_es, 8);  _es += __shfl_xor(_es, 16);                  \
    _es += __shfl_xor(_es, 32);                                              \
    float _den = _es + __expf(-_m);                                          \
    float _c = ai_s[_i] * _e / _den;                                         \
    _Pragma("unroll")                                                        \
    for (int _j = 0; _j < 32; ++_j) vjp[_j] = fmaf(_c, (V)[_j], vjp[_j]);    \
} while (0)

#define RMERGE(WRITEOUT) do {                                                \
    __syncthreads();                                                         \
    _Pragma("unroll")                                                        \
    for (int _j = 0; _j < 32; ++_j) BSLOT(wv, lane, _j) = vjp[_j];           \
    __syncthreads();                                                         \
    if (wv == 0) {                                                           \
        float _tot[32];                                                      \
        _Pragma("unroll")                                                    \
        for (int _j = 0; _j < 32; ++_j) {                                    \
            float _s = 0.f;                                                  \
            _Pragma("unroll")                                                \
            for (int _w = 0; _w < 16; ++_w) _s += BSLOT(_w, lane, _j);       \
            _tot[_j] = _s; }                                                 \
        float _ss = 0.f;                                                     \
        _Pragma("unroll")                                                    \
        for (int _j = 0; _j < 32; ++_j) _ss = fmaf(_tot[_j], _tot[_j], _ss); \
        _ss += __shfl_xor(_ss, 1);                                           \
        float _nr = sqrtf(_ss);                                              \
        float _f = (_ss / (_ss + 1.0f)) / (_nr + EPS);                       \
        _Pragma("unroll")                                                    \
        for (int _j = 0; _j < 32; ++_j) {                                    \
            float _v = _f * _tot[_j];                                        \
            BSLOT(0, lane, _j) = _v;                                         \
            if (WRITEOUT) out[(size_t)n * 2048 + base + _j] = _v;            \
        }                                                                    \
    }                                                                        \
    __syncthreads();                                                         \
    _Pragma("unroll")                                                        \
    for (int _j = 0; _j < 32; ++_j) vj[_j] = BSLOT(0, lane, _j);             \
} while (0)

__global__ __launch_bounds__(1024) __attribute__((amdgpu_waves_per_eu(4, 4)))
void k_route(
    const float* __restrict__ votes, const float* __restrict__ ai,
    float* __restrict__ out, int n0, int cnt)
{
    const int nl = blockIdx.x;
    const int n  = n0 + nl;
    const int t  = threadIdx.x;
    const int wv = t >> 6;          // 0..15
    const int lane = t & 63;
    const int o = lane >> 1;
    const int g = lane & 1;
    const int base = o * HDIM + g * 32;
    const int ib = wv * 8;

    __shared__ float buf[16][2048];     // 128 KB merge buffer
    __shared__ float bijl[NIN][NOUT + 1];
    __shared__ float ai_s[NIN];

    if (t < NIN) ai_s[t] = ai[(size_t)n * NIN + t];
    for (int idx = t; idx < NIN * (NOUT + 1); idx += 1024) ((float*)bijl)[idx] = 0.f;
    __syncthreads();

    const float* vb = votes + (size_t)nl * (NIN * NOUT * HDIM);

    float s[32], vj[32], vjp[32];

    // ---- pass 1: uniform coupling c = ai/33 ----
    #pragma unroll
    for (int j = 0; j < 32; ++j) vjp[j] = 0.f;
    #pragma unroll
    for (int k = 0; k < 8; ++k) {
        LOADSLAB(s, ib + k);
        float c = ai_s[ib + k] * (1.0f / 33.0f);
        #pragma unroll
        for (int j = 0; j < 32; ++j) vjp[j] = fmaf(c, s[j], vjp[j]);
    }
    RMERGE(false);

    // ---- pass 2 ----
    #pragma unroll
    for (int j = 0; j < 32; ++j) vjp[j] = 0.f;
    #pragma unroll
    for (int k = 0; k < 8; ++k) {
        LOADSLAB(s, ib + k);
        RBODY(s, ib + k);
    }
    RMERGE(false);

    // ---- pass 3 ----
    #pragma unroll
    for (int j = 0; j < 32; ++j) vjp[j] = 0.f;
    #pragma unroll
    for (int k = 0; k < 8; ++k) {
        LOADSLAB(s, ib + k);
        RBODY(s, ib + k);
    }
    RMERGE(true);
}

// ---------------------------------------------------------------------------
extern "C" void kernel_launch(void* const* d_in, const int* in_sizes, int n_in,
                              void* d_out, int out_size, void* d_ws, size_t ws_size,
                              hipStream_t stream)
{
    const float* x    = (const float*)d_in[0];
    const float* mask = (const float*)d_in[1];
    const float* Wcap = (const float*)d_in[2];
    const float* Bcap = (const float*)d_in[3];
    const float* Wv   = (const float*)d_in[4];
    const float* Bv   = (const float*)d_in[5];
    float* out = (float*)d_out;

    char* ws = (char*)d_ws;
    unsigned short* u_hi = (unsigned short*)ws;              //  4,194,304
    unsigned short* u_lo = (unsigned short*)(ws + 4194304);  //  4,194,304
    float*          ai   = (float*)(ws + 8388608);           //    131,072
    unsigned short* Wth  = (unsigned short*)(ws + 8519680);  // 33,554,432
    unsigned short* Wtl  = (unsigned short*)(ws + 42074112); // 33,554,432
    float*          votes= (float*)(ws + 75628544);          // chunk * 1 MB

    size_t avail = ws_size > 75628544ull ? ws_size - 75628544ull : 0;
    int chunk = 256;
    while (chunk > 4 && (size_t)chunk * 1048576ull > avail) chunk >>= 1;

    k_u_ai<<<dim3(NIN, 4), 256, 0, stream>>>(x, Wcap, Bcap, u_hi, u_lo, ai);
    k_wconv<<<NIN * NOUT, 256, 0, stream>>>(Wv, Wth, Wtl);

    for (int cc0 = 0; cc0 < NB; cc0 += chunk) {
        int cnt = (NB - cc0) < chunk ? (NB - cc0) : chunk;
        k_votes<<<dim3(NIN, 16), 256, 0, stream>>>(u_hi, u_lo, Wth, Wtl, Bv, mask, votes, cc0, cnt);
        k_route<<<cnt, 1024, 0, stream>>>(votes, ai, out, cc0, cnt);
    }
}

// Round 7
// 698.895 us; speedup vs baseline: 1.4444x; 1.4260x over previous
//
#include <hip/hip_runtime.h>

#define NB    256
#define NIN   128
#define DD    256
#define NOUT  32
#define HDIM  64
#define EPS   1e-8f

typedef __attribute__((ext_vector_type(8))) short short8v;
typedef __attribute__((ext_vector_type(4))) float float4v;

__device__ __forceinline__ unsigned short f2bf(float f) {
    unsigned u = __float_as_uint(f);
    u += 0x7fffu + ((u >> 16) & 1u);
    return (unsigned short)(u >> 16);
}
__device__ __forceinline__ float bf2f(unsigned short h) {
    return __uint_as_float(((unsigned)h) << 16);
}

// ---------------------------------------------------------------------------
// K1: u = squash(x·Wcap + Bcap) -> u_hi/u_lo (bf16 split), ai = ||u||
// ---------------------------------------------------------------------------
__global__ __launch_bounds__(256, 2) void k_u_ai(
    const float* __restrict__ x, const float* __restrict__ Wcap,
    const float* __restrict__ Bcap, unsigned short* __restrict__ u_hi,
    unsigned short* __restrict__ u_lo, float* __restrict__ ai)
{
    const int i  = blockIdx.x;          // 0..127
    const int n0 = blockIdx.y * 64;     // 0,64,128,192
    const int t  = threadIdx.x;

    __shared__ float Wl[128][68];       // half of Wcap[i]: [128 d][64 h]
    __shared__ float xl[64][132];       // x tile: [64 n][128 d]

    const int tn = t >> 4, th = t & 15;
    const int hbase = th * 4;

    float acc[4][4];
    {
        const float4 b = *(const float4*)(Bcap + i * 64 + hbase);
        #pragma unroll
        for (int r = 0; r < 4; ++r) { acc[r][0]=b.x; acc[r][1]=b.y; acc[r][2]=b.z; acc[r][3]=b.w; }
    }

    for (int half = 0; half < 2; ++half) {
        const float4* wsrc = (const float4*)(Wcap + (size_t)i * DD * 64 + (size_t)half * 128 * 64);
        #pragma unroll
        for (int p = 0; p < 8; ++p) {
            int k = t + p * 256;
            float4 v = wsrc[k];
            int d = k >> 4, h4 = (k & 15) * 4;
            *(float4*)&Wl[d][h4] = v;
        }
        #pragma unroll
        for (int p = 0; p < 8; ++p) {
            int k = t + p * 256;
            int row = k >> 5, c4 = (k & 31) * 4;
            float4 v = *(const float4*)(x + ((size_t)(n0 + row) * NIN + i) * DD + half * 128 + c4);
            *(float4*)&xl[row][c4] = v;
        }
        __syncthreads();
        #pragma unroll 4
        for (int d = 0; d < 128; ++d) {
            float a0 = xl[tn*4+0][d], a1 = xl[tn*4+1][d], a2 = xl[tn*4+2][d], a3 = xl[tn*4+3][d];
            float w0 = Wl[d][hbase+0], w1 = Wl[d][hbase+1], w2 = Wl[d][hbase+2], w3 = Wl[d][hbase+3];
            acc[0][0]=fmaf(a0,w0,acc[0][0]); acc[0][1]=fmaf(a0,w1,acc[0][1]); acc[0][2]=fmaf(a0,w2,acc[0][2]); acc[0][3]=fmaf(a0,w3,acc[0][3]);
            acc[1][0]=fmaf(a1,w0,acc[1][0]); acc[1][1]=fmaf(a1,w1,acc[1][1]); acc[1][2]=fmaf(a1,w2,acc[1][2]); acc[1][3]=fmaf(a1,w3,acc[1][3]);
            acc[2][0]=fmaf(a2,w0,acc[2][0]); acc[2][1]=fmaf(a2,w1,acc[2][1]); acc[2][2]=fmaf(a2,w2,acc[2][2]); acc[2][3]=fmaf(a2,w3,acc[2][3]);
            acc[3][0]=fmaf(a3,w0,acc[3][0]); acc[3][1]=fmaf(a3,w1,acc[3][1]); acc[3][2]=fmaf(a3,w2,acc[3][2]); acc[3][3]=fmaf(a3,w3,acc[3][3]);
        }
        __syncthreads();
    }

    #pragma unroll
    for (int r = 0; r < 4; ++r) {
        float s = acc[r][0]*acc[r][0] + acc[r][1]*acc[r][1] + acc[r][2]*acc[r][2] + acc[r][3]*acc[r][3];
        s += __shfl_xor(s, 1); s += __shfl_xor(s, 2); s += __shfl_xor(s, 4); s += __shfl_xor(s, 8);
        float n2 = s, nrm = sqrtf(n2);
        float f = (n2 / (n2 + 1.0f)) / (nrm + EPS);
        int n = n0 + tn * 4 + r;
        float v0 = f*acc[r][0], v1 = f*acc[r][1], v2 = f*acc[r][2], v3 = f*acc[r][3];
        unsigned short ha = f2bf(v0), hb = f2bf(v1), hc = f2bf(v2), hd = f2bf(v3);
        unsigned short la = f2bf(v0 - bf2f(ha)), lb = f2bf(v1 - bf2f(hb));
        unsigned short lc = f2bf(v2 - bf2f(hc)), ld = f2bf(v3 - bf2f(hd));
        size_t eo = ((size_t)n * NIN + i) * HDIM + hbase;
        *(uint2*)(u_hi + eo) = make_uint2((unsigned)ha | ((unsigned)hb << 16), (unsigned)hc | ((unsigned)hd << 16));
        *(uint2*)(u_lo + eo) = make_uint2((unsigned)la | ((unsigned)lb << 16), (unsigned)lc | ((unsigned)ld << 16));
        if (th == 0) ai[(size_t)n * NIN + i] = f * nrm;
    }
}

// ---------------------------------------------------------------------------
// K1b: Wv [io][d][h] f32 -> Wt_hi/Wt_lo [io][h][d] bf16 (transpose + split)
// ---------------------------------------------------------------------------
__global__ __launch_bounds__(256, 4) void k_wconv(
    const float* __restrict__ Wv, unsigned short* __restrict__ Wth,
    unsigned short* __restrict__ Wtl)
{
    const int io = blockIdx.x;
    const int t  = threadIdx.x;
    __shared__ float tile[64][68];

    const float4* src = (const float4*)(Wv + (size_t)io * 4096);
    const int d = t >> 2, hb = (t & 3) * 16;
    #pragma unroll
    for (int q = 0; q < 4; ++q) {
        float4 v = src[t * 4 + q];
        *(float4*)&tile[d][hb + q * 4] = v;
    }
    __syncthreads();
    const int h = t >> 2, d0 = (t & 3) * 16;
    unsigned hp[8], lp[8];
    #pragma unroll
    for (int j = 0; j < 8; ++j) {
        float fa = tile[d0 + 2*j][h], fb = tile[d0 + 2*j + 1][h];
        unsigned short ha = f2bf(fa), hbb = f2bf(fb);
        unsigned short la = f2bf(fa - bf2f(ha)), lb = f2bf(fb - bf2f(hbb));
        hp[j] = (unsigned)ha | ((unsigned)hbb << 16);
        lp[j] = (unsigned)la | ((unsigned)lb << 16);
    }
    size_t eo = (size_t)io * 4096 + (size_t)h * 64 + d0;
    *(uint4*)(Wth + eo)     = make_uint4(hp[0], hp[1], hp[2], hp[3]);
    *(uint4*)(Wth + eo + 8) = make_uint4(hp[4], hp[5], hp[6], hp[7]);
    *(uint4*)(Wtl + eo)     = make_uint4(lp[0], lp[1], lp[2], lp[3]);
    *(uint4*)(Wtl + eo + 8) = make_uint4(lp[4], lp[5], lp[6], lp[7]);
}

// ---------------------------------------------------------------------------
// K2: votes via split-bf16 MFMA -> f16 PERMUTED layout.
// Element (n,i,o,h) stored at half-offset ((q*64 + o*2 + g)*8 + c) within the
// (n,i) slab of 2048 halfs, where g=h>>5, q=(h&31)>>3, c=h&7.  This makes
// k_route's per-instruction wave access a contiguous 1KB line.
// ---------------------------------------------------------------------------
__global__ __launch_bounds__(256, 3) void k_votes(
    const unsigned short* __restrict__ u_hi, const unsigned short* __restrict__ u_lo,
    const unsigned short* __restrict__ Wth, const unsigned short* __restrict__ Wtl,
    const float* __restrict__ Bv, const float* __restrict__ mask,
    _Float16* __restrict__ votes, int c0, int cnt)
{
    const int i   = blockIdx.x;
    const int op  = blockIdx.y;
    const int t   = threadIdx.x;
    const int iob = i * 32 + op * 2;

    __shared__ __align__(16) char lds[49920];
    float* biasl = (float*)(lds + 49152);
    float* msk   = (float*)(lds + 49664);

    {   // stage B once
        const int o = t >> 7, cc = t & 127;
        #pragma unroll
        for (int q = 0; q < 4; ++q) {
            int c = cc + q * 128;
            int h = c >> 3, dby = (c & 7) * 16;
            size_t gb = (size_t)(iob + o) * 8192 + (size_t)c * 16;
            uint4 vh = *(const uint4*)((const char*)Wth + gb);
            uint4 vl = *(const uint4*)((const char*)Wtl + gb);
            int lb = o * 16384 + h * 128 + (dby ^ ((h & 7) << 4));
            *(uint4*)(lds + lb)        = vh;
            *(uint4*)(lds + lb + 8192) = vl;
        }
    }
    if (t < 128) biasl[t] = Bv[(size_t)(iob + (t >> 6)) * 64 + (t & 63)];

    const int w = t >> 6, lane = t & 63;
    const int o_l = w & 1, mi0 = (w >> 1) * 2;
    const int lr = lane & 15, lg = lane >> 4;

    const int nzn = (cnt + 63) >> 6;
    for (int nz = 0; nz < nzn; ++nz) {
        const int nbase = nz * 64;
        __syncthreads();
        {   // stage A
            const int n = t >> 2, s = t & 3;
            bool ok = (nbase + n) < cnt;
            size_t gb = ((size_t)(c0 + nbase + n) * NIN + i) * HDIM * 2;
            #pragma unroll
            for (int p = 0; p < 2; ++p) {
                int dby = s * 32 + p * 16;
                int lb = 32768 + n * 128 + (dby ^ ((n & 7) << 4));
                uint4 vh = ok ? *(const uint4*)((const char*)u_hi + gb + dby) : make_uint4(0,0,0,0);
                uint4 vl = ok ? *(const uint4*)((const char*)u_lo + gb + dby) : make_uint4(0,0,0,0);
                *(uint4*)(lds + lb)        = vh;
                *(uint4*)(lds + lb + 8192) = vl;
            }
        }
        if (t < 64) msk[t] = ((nbase + t) < cnt) ? mask[(size_t)(c0 + nbase + t) * NIN + i] : 0.f;
        __syncthreads();

        float4v acc[2][4];
        #pragma unroll
        for (int a = 0; a < 2; ++a)
            #pragma unroll
            for (int b = 0; b < 4; ++b)
                acc[a][b] = (float4v){0.f, 0.f, 0.f, 0.f};

        #pragma unroll
        for (int ks = 0; ks < 2; ++ks) {
            const int colby = ks * 64 + lg * 16;
            short8v ah[2], al[2], bh[4], bl[4];
            #pragma unroll
            for (int mi = 0; mi < 2; ++mi) {
                int row = (mi0 + mi) * 16 + lr;
                int ob = 32768 + row * 128 + (colby ^ ((row & 7) << 4));
                ah[mi] = *(const short8v*)(lds + ob);
                al[mi] = *(const short8v*)(lds + ob + 8192);
            }
            #pragma unroll
            for (int ni = 0; ni < 4; ++ni) {
                int hrow = ni * 16 + lr;
                int ob = o_l * 16384 + hrow * 128 + (colby ^ ((hrow & 7) << 4));
                bh[ni] = *(const short8v*)(lds + ob);
                bl[ni] = *(const short8v*)(lds + ob + 8192);
            }
            #pragma unroll
            for (int mi = 0; mi < 2; ++mi)
                #pragma unroll
                for (int ni = 0; ni < 4; ++ni) {
                    acc[mi][ni] = __builtin_amdgcn_mfma_f32_16x16x32_bf16(ah[mi], bh[ni], acc[mi][ni], 0, 0, 0);
                    acc[mi][ni] = __builtin_amdgcn_mfma_f32_16x16x32_bf16(al[mi], bh[ni], acc[mi][ni], 0, 0, 0);
                    acc[mi][ni] = __builtin_amdgcn_mfma_f32_16x16x32_bf16(ah[mi], bl[ni], acc[mi][ni], 0, 0, 0);
                }
        }

        #pragma unroll
        for (int mi = 0; mi < 2; ++mi) {
            #pragma unroll
            for (int r = 0; r < 4; ++r) {
                int n_loc = (mi0 + mi) * 16 + lg * 4 + r;
                if (nbase + n_loc < cnt) {
                    float mv = msk[n_loc];
                    size_t sb = ((size_t)(nbase + n_loc) * NIN + i) * 2048;
                    #pragma unroll
                    for (int ni = 0; ni < 4; ++ni) {
                        int h = ni * 16 + lr;
                        float val = (acc[mi][ni][r] + biasl[o_l * 64 + h]) * mv;
                        int q2 = ((ni & 1) << 1) | (lr >> 3);
                        int off = (q2 * 64 + (op * 2 + o_l) * 2 + (ni >> 1)) * 8 + (lr & 7);
                        votes[sb + off] = (_Float16)val;
                    }
                }
            }
        }
    }
}

// ---------------------------------------------------------------------------
// K3 v6: 3-pass routing, f16 permuted votes.  1024 threads = 16 waves,
// 8 i per wave.  Each LOADSLAB instruction reads a contiguous 1KB across the
// wave (uint4 index = q*64 + lane).  Merge via rotated BSLOT tree.
// ---------------------------------------------------------------------------
#define BSLOT(W, LN, J) buf[(W)][((LN) << 5) + (((J) + (LN)) & 31)]

#define LOADSLAB(DST, IDX) do {                                              \
    const uint4* _p = (const uint4*)(vb + (size_t)(IDX) * 2048) + lane;      \
    _Pragma("unroll")                                                        \
    for (int _q = 0; _q < 4; ++_q) {                                         \
        uint4 _v = _p[_q * 64];                                              \
        const _Float16* _h = (const _Float16*)&_v;                           \
        _Pragma("unroll")                                                    \
        for (int _c = 0; _c < 8; ++_c) (DST)[_q*8+_c] = (float)_h[_c];       \
    }                                                                        \
} while (0)

#define RBODY(V, I) do {                                                     \
    const int _i = (I);                                                      \
    float _ag = 0.f;                                                         \
    _Pragma("unroll")                                                        \
    for (int _j = 0; _j < 32; ++_j) _ag = fmaf((V)[_j], vj[_j], _ag);        \
    _ag += __shfl_xor(_ag, 1);                                               \
    float _b = bijl[_i][o] + _ag;                                            \
    if (g == 0) bijl[_i][o] = _b;                                            \
    float _m = _b;                                                           \
    _m = fmaxf(_m, __shfl_xor(_m, 2));  _m = fmaxf(_m, __shfl_xor(_m, 4));   \
    _m = fmaxf(_m, __shfl_xor(_m, 8));  _m = fmaxf(_m, __shfl_xor(_m, 16));  \
    _m = fmaxf(_m, __shfl_xor(_m, 32));                                      \
    _m = fmaxf(_m, 0.f);                                                     \
    float _e = __expf(_b - _m);                                              \
    float _es = _e;                                                          \
    _es += __shfl_xor(_es, 2);  _es += __shfl_xor(_es, 4);                   \
    _es += __shfl_xor(_es, 8);  _es += __shfl_xor(_es, 16);                  \
    _es += __shfl_xor(_es, 32);                                              \
    float _den = _es + __expf(-_m);                                          \
    float _c = ai_s[_i] * _e / _den;                                         \
    _Pragma("unroll")                                                        \
    for (int _j = 0; _j < 32; ++_j) vjp[_j] = fmaf(_c, (V)[_j], vjp[_j]);    \
} while (0)

#define RMERGE(WRITEOUT) do {                                                \
    __syncthreads();                                                         \
    _Pragma("unroll")                                                        \
    for (int _j = 0; _j < 32; ++_j) BSLOT(wv, lane, _j) = vjp[_j];           \
    __syncthreads();                                                         \
    if (wv == 0) {                                                           \
        float _tot[32];                                                      \
        _Pragma("unroll")                                                    \
        for (int _j = 0; _j < 32; ++_j) {                                    \
            float _s = 0.f;                                                  \
            _Pragma("unroll")                                                \
            for (int _w = 0; _w < 16; ++_w) _s += BSLOT(_w, lane, _j);       \
            _tot[_j] = _s; }                                                 \
        float _ss = 0.f;                                                     \
        _Pragma("unroll")                                                    \
        for (int _j = 0; _j < 32; ++_j) _ss = fmaf(_tot[_j], _tot[_j], _ss); \
        _ss += __shfl_xor(_ss, 1);                                           \
        float _nr = sqrtf(_ss);                                              \
        float _f = (_ss / (_ss + 1.0f)) / (_nr + EPS);                       \
        _Pragma("unroll")                                                    \
        for (int _j = 0; _j < 32; ++_j) {                                    \
            float _v = _f * _tot[_j];                                        \
            BSLOT(0, lane, _j) = _v;                                         \
            if (WRITEOUT) out[(size_t)n * 2048 + base + _j] = _v;            \
        }                                                                    \
    }                                                                        \
    __syncthreads();                                                         \
    _Pragma("unroll")                                                        \
    for (int _j = 0; _j < 32; ++_j) vj[_j] = BSLOT(0, lane, _j);             \
} while (0)

__global__ __launch_bounds__(1024) __attribute__((amdgpu_waves_per_eu(4, 4)))
void k_route(
    const _Float16* __restrict__ votes, const float* __restrict__ ai,
    float* __restrict__ out, int n0, int cnt)
{
    const int nl = blockIdx.x;
    const int n  = n0 + nl;
    const int t  = threadIdx.x;
    const int wv = t >> 6;          // 0..15
    const int lane = t & 63;
    const int o = lane >> 1;
    const int g = lane & 1;
    const int base = o * HDIM + g * 32;
    const int ib = wv * 8;

    __shared__ float buf[16][2048];     // 128 KB merge buffer
    __shared__ float bijl[NIN][NOUT + 1];
    __shared__ float ai_s[NIN];

    if (t < NIN) ai_s[t] = ai[(size_t)n * NIN + t];
    for (int idx = t; idx < NIN * (NOUT + 1); idx += 1024) ((float*)bijl)[idx] = 0.f;
    __syncthreads();

    const _Float16* vb = votes + (size_t)nl * (NIN * NOUT * HDIM);

    float s[32], vj[32], vjp[32];

    // ---- pass 1: uniform coupling c = ai/33 ----
    #pragma unroll
    for (int j = 0; j < 32; ++j) vjp[j] = 0.f;
    #pragma unroll
    for (int k = 0; k < 8; ++k) {
        LOADSLAB(s, ib + k);
        float c = ai_s[ib + k] * (1.0f / 33.0f);
        #pragma unroll
        for (int j = 0; j < 32; ++j) vjp[j] = fmaf(c, s[j], vjp[j]);
    }
    RMERGE(false);

    // ---- pass 2 ----
    #pragma unroll
    for (int j = 0; j < 32; ++j) vjp[j] = 0.f;
    #pragma unroll
    for (int k = 0; k < 8; ++k) {
        LOADSLAB(s, ib + k);
        RBODY(s, ib + k);
    }
    RMERGE(false);

    // ---- pass 3 ----
    #pragma unroll
    for (int j = 0; j < 32; ++j) vjp[j] = 0.f;
    #pragma unroll
    for (int k = 0; k < 8; ++k) {
        LOADSLAB(s, ib + k);
        RBODY(s, ib + k);
    }
    RMERGE(true);
}

// ---------------------------------------------------------------------------
extern "C" void kernel_launch(void* const* d_in, const int* in_sizes, int n_in,
                              void* d_out, int out_size, void* d_ws, size_t ws_size,
                              hipStream_t stream)
{
    const float* x    = (const float*)d_in[0];
    const float* mask = (const float*)d_in[1];
    const float* Wcap = (const float*)d_in[2];
    const float* Bcap = (const float*)d_in[3];
    const float* Wv   = (const float*)d_in[4];
    const float* Bv   = (const float*)d_in[5];
    float* out = (float*)d_out;

    char* ws = (char*)d_ws;
    unsigned short* u_hi = (unsigned short*)ws;              //  4,194,304
    unsigned short* u_lo = (unsigned short*)(ws + 4194304);  //  4,194,304
    float*          ai   = (float*)(ws + 8388608);           //    131,072
    unsigned short* Wth  = (unsigned short*)(ws + 8519680);  // 33,554,432
    unsigned short* Wtl  = (unsigned short*)(ws + 42074112); // 33,554,432
    _Float16*       votes= (_Float16*)(ws + 75628544);       // chunk * 524,288 B

    size_t avail = ws_size > 75628544ull ? ws_size - 75628544ull : 0;
    int chunk = 256;
    while (chunk > 4 && (size_t)chunk * 524288ull > avail) chunk >>= 1;

    k_u_ai<<<dim3(NIN, 4), 256, 0, stream>>>(x, Wcap, Bcap, u_hi, u_lo, ai);
    k_wconv<<<NIN * NOUT, 256, 0, stream>>>(Wv, Wth, Wtl);

    for (int cc0 = 0; cc0 < NB; cc0 += chunk) {
        int cnt = (NB - cc0) < chunk ? (NB - cc0) : chunk;
        k_votes<<<dim3(NIN, 16), 256, 0, stream>>>(u_hi, u_lo, Wth, Wtl, Bv, mask, votes, cc0, cnt);
        k_route<<<cnt, 1024, 0, stream>>>(votes, ai, out, cc0, cnt);
    }
}